// Round 8
// baseline (592.621 us; speedup 1.0000x reference)
//
#include <hip/hip_runtime.h>

// ConvLSTM B=8,T=16,CIN=16,HID=64,H=W=64,K=3 'SAME' — 16-launch bf16 MFMA,
// ZERO-LDS step kernel. R6/R7 falsified B-traffic and K-chain-latency
// theories; remaining suspect is per-block phase overhead (LDS zero + 2
// barriers + staging). R8: SAME-padding lives in a bordered channel-last
// global buffer xh[b][66][66][96] (x 0..15 | h 16..79 | bias 80 | pad 81..95);
// A-frags load straight from global (64B-line-aligned per m), no LDS, no
// syncthreads. Step kernel = K-loop + epilogue only; it also writes h(t+1)
// and copies x(t+1) into the next xh buffer. c fp32 in place (channel-last).

#define B_ 8
#define T_ 16
#define CIN_ 16
#define HID_ 64
#define H_ 64
#define W_ 64
#define HW_ (H_*W_)
#define CTOT_ 80
#define XH_R 66
#define XH_C 96                     // pixel stride 192B = 3 cachelines, 64B aligned
#define XH_ROWS (XH_R*XH_C)         // 6336
#define XH_BAT (XH_R*XH_ROWS)       // 418176
#define XH_ELEMS (B_*XH_BAT)        // 3345408 halfwords = 6690816 B
#define CSTRIDE_ (B_*HID_*HW_)      // 2097152

typedef __attribute__((ext_vector_type(8))) short short8;
typedef __attribute__((ext_vector_type(4))) float f32x4;

__device__ __forceinline__ unsigned short f2bf(float f){
    unsigned u = __float_as_uint(f);
    u = (u + 0x7FFFu + ((u >> 16) & 1u)) >> 16;   // RNE
    return (unsigned short)u;
}
__device__ __forceinline__ float sigm_(float v){ return 1.0f/(1.0f + __expf(-v)); }
__device__ __forceinline__ float tanh_(float v){ return 2.0f/(1.0f + __expf(-2.0f*v)) - 1.0f; }

// Wfrag: [tap 9][cc 3][ng 16] frags of 512 hw ([lane][j]).
// n = ng*16+(lane&15): g=n>>6, o=n&63; k-ch c = cc*32+(lane>>4)*8+j.
// Bias folded at c==80 (constant-1 channel), center tap only.
__global__ void prep_wfrag(const float* __restrict__ Wf, const float* __restrict__ Wi,
                           const float* __restrict__ Wc, const float* __restrict__ Wo,
                           const float* __restrict__ bf, const float* __restrict__ bi,
                           const float* __restrict__ bc, const float* __restrict__ bo,
                           unsigned short* __restrict__ Wfrag){
    int idx = blockIdx.x*256 + threadIdx.x;          // 864*256 = 221184 exact
    int j    = idx & 7;
    int lane = (idx >> 3) & 63;
    int frag = idx >> 9;
    int ng = frag & 15;
    int tc = frag >> 4;
    int cc = tc % 3, tap = tc / 3;
    int n = ng*16 + (lane & 15);
    int g = n >> 6, o = n & 63;
    int c = cc*32 + ((lane >> 4) << 3) + j;
    int ky = tap / 3, kx = tap % 3;
    float v = 0.0f;
    if (c < CTOT_){
        if (g == 0)      v = Wf[((o*CTOT_ + c)*3 + ky)*3 + kx];
        else if (g == 1) v = Wi[((o*CTOT_ + c)*3 + ky)*3 + kx];
        else if (g == 2) v = Wc[((o*CTOT_ + c)*3 + ky)*3 + kx];
        else             v = (tap == 4) ? Wo[o*CTOT_ + c] : 0.0f;
    } else if (c == CTOT_ && tap == 4){              // bias channel
        v = (g==0) ? bf[o] : (g==1) ? bi[o] : (g==2) ? bc[o] : bo[o];
    }
    Wfrag[idx] = f2bf(v);
}

// zero both xh buffers (borders, h, pad channels)
__global__ void prep_zero(unsigned short* __restrict__ xhA){
    const int n8 = 2*XH_ELEMS/8;                     // uint4 count over both buffers
    uint4 z; z.x=z.y=z.z=z.w=0u;
    for (int i = blockIdx.x*256 + threadIdx.x; i < n8; i += 262144)
        ((uint4*)xhA)[i] = z;
}

// bias channel = 1.0 in both buffers; x(0) -> xhA interior
__global__ void prep_fill(const float* __restrict__ x,
                          unsigned short* __restrict__ xhA,
                          unsigned short* __restrict__ xhB){
    int idx = blockIdx.x*256 + threadIdx.x;          // 32768 = (b,y,px)
    int px = idx & 63, y = (idx >> 6) & 63, b = idx >> 12;
    const float* src = x + ((size_t)b*T_*CIN_)*HW_ + y*W_ + px;   // t = 0
    unsigned short tmp[16];
    #pragma unroll
    for (int c = 0; c < 16; ++c) tmp[c] = f2bf(src[(size_t)c*HW_]);
    unsigned short* dst = xhA + (size_t)b*XH_BAT + (y+1)*XH_ROWS + (px+1)*XH_C;
    *(uint4*)dst       = *(uint4*)tmp;
    *(uint4*)(dst + 8) = *(uint4*)(tmp + 8);
    // bias channel, both buffers, all 66x66 pixels
    for (int j = idx; j < 2*B_*XH_R*XH_R; j += 32768){
        unsigned short* base = (j < B_*XH_R*XH_R) ? xhA : xhB;
        int r = (j < B_*XH_R*XH_R) ? j : j - B_*XH_R*XH_R;
        base[(size_t)r*XH_C + CTOT_] = 0x3F80;       // bf16 1.0
    }
}

__global__ __launch_bounds__(256, 4) void lstm_step(
    const float* __restrict__ x,
    const unsigned short* __restrict__ Wfrag,
    const unsigned short* __restrict__ xh_cur,
    unsigned short* __restrict__ xh_next,
    float* __restrict__ cbuf,                        // [b][y][px][o] fp32 in place
    float* __restrict__ out,                         // [h|c] NCHW, t==15 only
    int t)
{
    const int id   = blockIdx.x;
    const int xcd  = id & 7;                         // XCD-local y band
    const int jj   = id >> 3;
    const int y    = xcd*8 + (jj & 7);
    const int b    = (jj >> 3) & 7;
    const int x0   = (jj >> 6) * 32;
    const int tid  = threadIdx.x;
    const int lane = tid & 63;
    const int w    = tid >> 6;
    const int l15  = lane & 15;
    const int q    = lane >> 4;

    const unsigned short* xb = xh_cur + (size_t)b*XH_BAT;

    f32x4 acc[4][2];
    #pragma unroll
    for (int g = 0; g < 4; ++g){ acc[g][0] = (f32x4)0.0f; acc[g][1] = (f32x4)0.0f; }

    const int ktot = t ? 27 : 9;                     // t==0: h==0 -> cc=0 only

    short8 aC[2], bC[3], bO;
    {   // preload kt=0: tap=0 (ky=0,kx=0), cc=0
        const unsigned short* ap = xb + (size_t)(y*XH_ROWS) + (x0 + l15)*XH_C + q*8;
        aC[0] = *(const short8*)ap;
        aC[1] = *(const short8*)(ap + 16*XH_C);
        const unsigned short* bp = Wfrag + ((size_t)w << 9) + lane*8;
        #pragma unroll
        for (int g = 0; g < 3; ++g) bC[g] = *(const short8*)(bp + ((size_t)(g*4) << 9));
    }
    #pragma unroll 1
    for (int kt = 0; kt < ktot; ++kt){
        const int tap = kt % 9;
        const int nk = kt + 1;
        const bool have = (nk < ktot);
        short8 aN[2], bN[3], bOn;
        if (have){
            const int nt = nk % 9, ncc = nk / 9;
            const int nky = nt/3, nkx = nt - 3*(nt/3);
            const unsigned short* ap =
                xb + (size_t)((y + nky)*XH_ROWS) + (x0 + l15 + nkx)*XH_C + ncc*32 + q*8;
            aN[0] = *(const short8*)ap;
            aN[1] = *(const short8*)(ap + 16*XH_C);
            const unsigned short* bp =
                Wfrag + ((size_t)((nt*3 + ncc)*16 + w) << 9) + lane*8;
            #pragma unroll
            for (int g = 0; g < 3; ++g) bN[g] = *(const short8*)(bp + ((size_t)(g*4) << 9));
            if (nt == 4)
                bOn = *(const short8*)(Wfrag + ((size_t)((4*3 + nk/9)*16 + 12 + w) << 9) + lane*8);
        }
        if (tap == 4){
            acc[3][0] = __builtin_amdgcn_mfma_f32_16x16x32_bf16(aC[0], bO, acc[3][0], 0,0,0);
            acc[3][1] = __builtin_amdgcn_mfma_f32_16x16x32_bf16(aC[1], bO, acc[3][1], 0,0,0);
        }
        #pragma unroll
        for (int g = 0; g < 3; ++g){
            acc[g][0] = __builtin_amdgcn_mfma_f32_16x16x32_bf16(aC[0], bC[g], acc[g][0], 0,0,0);
            acc[g][1] = __builtin_amdgcn_mfma_f32_16x16x32_bf16(aC[1], bC[g], acc[g][1], 0,0,0);
        }
        if (have){
            aC[0]=aN[0]; aC[1]=aN[1];
            bC[0]=bN[0]; bC[1]=bN[1]; bC[2]=bN[2];
            if (nk % 9 == 4) bO = bOn;
        }
    }

    // ---- epilogue: wave-local gates; c in place; h(t+1) into bordered buffer
    const int o = w*16 + l15;
    unsigned short* xnb = xh_next + (size_t)b*XH_BAT;
    #pragma unroll
    for (int mf = 0; mf < 2; ++mf){
        #pragma unroll
        for (int r = 0; r < 4; ++r){
            const int m = mf*16 + q*4 + r;
            const int pxg = x0 + m;
            const float fv = sigm_(acc[0][mf][r]);
            const float iv = sigm_(acc[1][mf][r]);
            const float gv = tanh_(acc[2][mf][r]);
            const float ov = sigm_(acc[3][mf][r]);
            const size_t cidx = (((size_t)(b*H_ + y)*W_ + pxg)*HID_ + o);
            const float cprev = t ? cbuf[cidx] : 0.0f;
            const float cn = cprev*fv + iv*gv;
            const float hn = tanh_(cn)*ov;
            if (t < T_-1){
                cbuf[cidx] = cn;
                xnb[(size_t)(y+1)*XH_ROWS + (pxg+1)*XH_C + CIN_ + o] = f2bf(hn);
            } else {
                const size_t oidx = ((((size_t)(b*HID_ + o))*H_ + y)*W_ + pxg);
                out[oidx] = hn;
                out[CSTRIDE_ + oidx] = cn;
            }
        }
    }

    // ---- copy x(t+1) into xh_next (512 scalars: 16 ch x 32 px)
    if (t < T_-1){
        #pragma unroll
        for (int it = 0; it < 2; ++it){
            const int item = tid + it*256;
            const int c = item >> 5, px = item & 31;
            const float v = x[((size_t)(b*T_ + t + 1)*CIN_ + c)*HW_ + y*W_ + x0 + px];
            xnb[(size_t)(y+1)*XH_ROWS + (x0 + px + 1)*XH_C + c] = f2bf(v);
        }
    }
}

extern "C" void kernel_launch(void* const* d_in, const int* in_sizes, int n_in,
                              void* d_out, int out_size, void* d_ws, size_t ws_size,
                              hipStream_t stream){
    const float* x  = (const float*)d_in[0];
    const float* Wf = (const float*)d_in[1];
    const float* bf = (const float*)d_in[2];
    const float* Wi = (const float*)d_in[3];
    const float* bi = (const float*)d_in[4];
    const float* Wc = (const float*)d_in[5];
    const float* bc = (const float*)d_in[6];
    const float* Wo = (const float*)d_in[7];
    const float* bo = (const float*)d_in[8];

    // ws: Wfrag 442368 | cbuf 8388608 | xhA 6690816 | xhB 6690816  (= 22.2 MB)
    unsigned short* Wfrag = (unsigned short*)d_ws;
    float*          cbuf  = (float*)((char*)d_ws + 442368);
    unsigned short* xhA   = (unsigned short*)((char*)d_ws + 442368 + 8388608);
    unsigned short* xhB   = xhA + XH_ELEMS;

    prep_wfrag<<<dim3(864), dim3(256), 0, stream>>>(Wf, Wi, Wc, Wo, bf, bi, bc, bo, Wfrag);
    prep_zero<<<dim3(1024), dim3(256), 0, stream>>>(xhA);
    prep_fill<<<dim3(128), dim3(256), 0, stream>>>(x, xhA, xhB);

    for (int t = 0; t < T_; ++t){
        const unsigned short* xc = (t & 1) ? xhB : xhA;
        unsigned short*       xn = (t & 1) ? xhA : xhB;
        lstm_step<<<dim3(1024), dim3(256), 0, stream>>>(
            x, Wfrag, xc, xn, cbuf, (float*)d_out, t);
    }
}

// Round 9
// 439.195 us; speedup vs baseline: 1.3493x; 1.3493x over previous
//
#include <hip/hip_runtime.h>

// ConvLSTM B=8,T=16,CIN=16,HID=64,H=W=64,K=3 'SAME' — 16-launch bf16 MFMA.
// Model (R5-R8 evidence): per-XCD L2 traffic for B-fragments is the floor and
// scales with block count -> want M=64 (512 blocks, 6.4us/step B-floor), but
// R6 lost it to 3 blocks/CU occupancy (LDS 41.2KB). R9: shrink LDS tile to
// 88 ch/px (x16|h64|bias|7pad, 34.9KB) -> M=64 AND 4 blocks/CU (16 waves).
// cc2's K=32 A-window overreads 8 channels into the next pixel; their weights
// are zero so the product vanishes. Staging writes zeros on OOB -> no LDS
// zero pass, ONE barrier per step. A loads at body top (LDS latency hidden
// by 4 waves/SIMD), B depth-1 prefetch (L2 latency). Bias = channel 80 at
// center tap; o-gate center-tap only; x pre-converted bf16 channel-last;
// c fp32 in place channel-last; h ping-pong bf16 channel-last.

#define B_ 8
#define T_ 16
#define CIN_ 16
#define HID_ 64
#define H_ 64
#define W_ 64
#define HW_ (H_*W_)
#define CTOT_ 80
#define XS_ROW 66                   // 64 px + 2 halo
#define XS_CH 88                    // x16|h64|bias|7pad; 176B px stride, 16B aligned
#define XS_SIZE (3*XS_ROW*XS_CH)    // 17424 hw
#define XS_ALLOC (XS_SIZE + 16)     // +16 hw slack: last-pixel cc2 overread stays in-bounds
#define CSTRIDE_ (B_*HID_*HW_)      // 2097152

typedef __attribute__((ext_vector_type(8))) short short8;
typedef __attribute__((ext_vector_type(4))) float f32x4;

__device__ __forceinline__ unsigned short f2bf(float f){
    unsigned u = __float_as_uint(f);
    u = (u + 0x7FFFu + ((u >> 16) & 1u)) >> 16;   // RNE
    return (unsigned short)u;
}
__device__ __forceinline__ float sigm_(float v){ return 1.0f/(1.0f + __expf(-v)); }
__device__ __forceinline__ float tanh_(float v){ return 2.0f/(1.0f + __expf(-2.0f*v)) - 1.0f; }

// Wfrag: [tap 9][cc 3][ng 16] frags of 512 hw ([lane][j]).
// n = ng*16+(lane&15): g=n>>6, o=n&63; k-ch c = cc*32+(lane>>4)*8+j.
// c: 0..15 x, 16..79 h, 80 bias (center tap), 81..95 zero.
__global__ void prep_wfrag(const float* __restrict__ Wf, const float* __restrict__ Wi,
                           const float* __restrict__ Wc, const float* __restrict__ Wo,
                           const float* __restrict__ bf, const float* __restrict__ bi,
                           const float* __restrict__ bc, const float* __restrict__ bo,
                           unsigned short* __restrict__ Wfrag){
    int idx = blockIdx.x*256 + threadIdx.x;          // 864*256 = 221184 exact
    int j    = idx & 7;
    int lane = (idx >> 3) & 63;
    int frag = idx >> 9;
    int ng = frag & 15;
    int tc = frag >> 4;
    int cc = tc % 3, tap = tc / 3;
    int n = ng*16 + (lane & 15);
    int g = n >> 6, o = n & 63;
    int c = cc*32 + ((lane >> 4) << 3) + j;
    int ky = tap / 3, kx = tap % 3;
    float v = 0.0f;
    if (c < CTOT_){
        if (g == 0)      v = Wf[((o*CTOT_ + c)*3 + ky)*3 + kx];
        else if (g == 1) v = Wi[((o*CTOT_ + c)*3 + ky)*3 + kx];
        else if (g == 2) v = Wc[((o*CTOT_ + c)*3 + ky)*3 + kx];
        else             v = (tap == 4) ? Wo[o*CTOT_ + c] : 0.0f;
    } else if (c == CTOT_ && tap == 4){              // bias channel
        v = (g==0) ? bf[o] : (g==1) ? bi[o] : (g==2) ? bc[o] : bo[o];
    }
    Wfrag[idx] = f2bf(v);
}

// x[b][t][c][y][px] fp32 -> xbf[b][t][y][px][c16] bf16
__global__ void prep_xbf(const float* __restrict__ x, unsigned short* __restrict__ xbf){
    int idx = blockIdx.x*256 + threadIdx.x;          // 524288 = (b,t,y,px) flat
    int px = idx & 63;
    int y  = (idx >> 6) & 63;
    int bt = idx >> 12;
    const float* src = x + (size_t)bt*CIN_*HW_ + y*W_ + px;
    unsigned short tmp[16];
    #pragma unroll
    for (int c = 0; c < 16; ++c) tmp[c] = f2bf(src[(size_t)c*HW_]);
    uint4* dst = (uint4*)(xbf + (size_t)idx*16);
    dst[0] = *(uint4*)(tmp);
    dst[1] = *(uint4*)(tmp + 8);
}

__global__ __launch_bounds__(256, 4) void lstm_step(
    const unsigned short* __restrict__ xbf,
    const unsigned short* __restrict__ Wfrag,
    float* __restrict__ cbuf,                        // [b][y][px][o] fp32, in place
    const unsigned short* __restrict__ hin,          // [b][y][px][o] bf16
    unsigned short* __restrict__ hout,
    float* __restrict__ out,                         // [h|c] NCHW, t==15 only
    int t)
{
    __shared__ __align__(16) unsigned short Xs[XS_ALLOC];
    const int id   = blockIdx.x;
    // XCD swizzle: id&7 -> XCD; contiguous 8-row y band per XCD for halo locality.
    const int xcd  = id & 7;
    const int jj   = id >> 3;
    const int y    = xcd*8 + (jj & 7);
    const int b    = jj >> 3;
    const int tid  = threadIdx.x;
    const int lane = tid & 63;
    const int w    = tid >> 6;
    const int l15  = lane & 15;
    const int q    = lane >> 4;

    uint4 z4; z4.x=z4.y=z4.z=z4.w=0u;

    // ---- stage x (ch 0..15): 3 rows x 66 px x 2 ch8 = 396 uint4, zero OOB
    for (int i = tid; i < 396; i += 256){
        int row = i/132, rem = i - row*132;
        int px = rem >> 1, ch8 = rem & 1;
        int yy = y + row - 1, pxg = px - 1;
        uint4 v = z4;
        if (yy >= 0 && yy < H_ && pxg >= 0 && pxg < W_)
            v = *(const uint4*)(xbf + ((((size_t)(b*T_ + t)*H_ + yy)*W_ + pxg)*16 + ch8*8));
        *(uint4*)(Xs + (row*XS_ROW + px)*XS_CH + ch8*8) = v;
    }
    // ---- stage h (ch 16..79): 3 x 66 x 8 = 1584 uint4, zero OOB / zero at t==0
    for (int i = tid; i < 1584; i += 256){
        int row = i/528, rem = i - row*528;
        int px = rem >> 3, ch8 = rem & 7;
        int yy = y + row - 1, pxg = px - 1;
        uint4 v = z4;
        if (t > 0 && yy >= 0 && yy < H_ && pxg >= 0 && pxg < W_)
            v = *(const uint4*)(hin + ((((size_t)b*H_ + yy)*W_ + pxg)*HID_ + ch8*8));
        *(uint4*)(Xs + (row*XS_ROW + px)*XS_CH + CIN_ + ch8*8) = v;
    }
    // ---- bias chunk (ch 80..87): bf16 1.0 at ch80, zeros elsewhere
    {
        uint4 bias4; bias4.x = 0x00003F80u; bias4.y = bias4.z = bias4.w = 0u;
        for (int i = tid; i < 198; i += 256){
            int row = i/66, px = i - row*66;
            *(uint4*)(Xs + (row*XS_ROW + px)*XS_CH + 80) = bias4;
        }
        if (tid < 2) ((uint4*)Xs)[XS_SIZE/8 + tid] = z4;   // slack
    }
    __syncthreads();                                   // the ONLY barrier

    // ---- K-loop: cc outer (runtime), 9 taps unrolled; A at body top, B depth-1
    f32x4 acc[4][4];
    #pragma unroll
    for (int g = 0; g < 4; ++g)
        #pragma unroll
        for (int mf = 0; mf < 4; ++mf) acc[g][mf] = (f32x4)0.0f;

    short8 bC[3], bO;
    {   // preload B(cc=0, tap=0)
        const unsigned short* bp = Wfrag + ((size_t)w << 9) + lane*8;
        #pragma unroll
        for (int g = 0; g < 3; ++g) bC[g] = *(const short8*)(bp + ((size_t)(g*4) << 9));
    }
    #pragma unroll 1
    for (int cc = 0; cc < 3; ++cc){
        #pragma unroll
        for (int tap = 0; tap < 9; ++tap){
            const int ky = tap/3, kx = tap%3;
            // A(tap) from LDS
            short8 a[4];
            const unsigned short* ap =
                Xs + (size_t)(ky*XS_ROW + l15 + kx)*XS_CH + cc*32 + q*8;
            #pragma unroll
            for (int mf = 0; mf < 4; ++mf) a[mf] = *(const short8*)(ap + (size_t)(mf*16)*XS_CH);
            // B(next) prefetch
            short8 bN[3];
            const int nt = (tap == 8) ? 0 : tap + 1;
            const int nc = (tap == 8) ? cc + 1 : cc;
            if (nc < 3){
                const unsigned short* bp =
                    Wfrag + ((size_t)((nt*3 + nc)*16 + w) << 9) + lane*8;
                #pragma unroll
                for (int g = 0; g < 3; ++g) bN[g] = *(const short8*)(bp + ((size_t)(g*4) << 9));
            }
            if (tap == 3)   // o-gate frag for tap 4, this cc
                bO = *(const short8*)(Wfrag + ((size_t)((4*3 + cc)*16 + 12 + w) << 9) + lane*8);
            if (tap == 4){
                #pragma unroll
                for (int mf = 0; mf < 4; ++mf)
                    acc[3][mf] = __builtin_amdgcn_mfma_f32_16x16x32_bf16(a[mf], bO, acc[3][mf], 0,0,0);
            }
            #pragma unroll
            for (int g = 0; g < 3; ++g)
                #pragma unroll
                for (int mf = 0; mf < 4; ++mf)
                    acc[g][mf] = __builtin_amdgcn_mfma_f32_16x16x32_bf16(a[mf], bC[g], acc[g][mf], 0,0,0);
            if (nc < 3){ bC[0]=bN[0]; bC[1]=bN[1]; bC[2]=bN[2]; }
        }
    }

    // ---- epilogue: wave-local gates; c in place, channel-last
    const int o = w*16 + l15;
    #pragma unroll
    for (int mf = 0; mf < 4; ++mf){
        #pragma unroll
        for (int r = 0; r < 4; ++r){
            const int m = mf*16 + q*4 + r;                 // global pixel x
            const float fv = sigm_(acc[0][mf][r]);
            const float iv = sigm_(acc[1][mf][r]);
            const float gv = tanh_(acc[2][mf][r]);
            const float ov = sigm_(acc[3][mf][r]);
            const size_t cidx = (((size_t)(b*H_ + y)*W_ + m)*HID_ + o);
            const float cprev = t ? cbuf[cidx] : 0.0f;
            const float cn = cprev*fv + iv*gv;
            const float hn = tanh_(cn)*ov;
            if (t < T_-1){
                cbuf[cidx] = cn;
                hout[cidx] = f2bf(hn);
            } else {
                const size_t oidx = ((((size_t)(b*HID_ + o))*H_ + y)*W_ + m);
                out[oidx] = hn;
                out[CSTRIDE_ + oidx] = cn;
            }
        }
    }
}

extern "C" void kernel_launch(void* const* d_in, const int* in_sizes, int n_in,
                              void* d_out, int out_size, void* d_ws, size_t ws_size,
                              hipStream_t stream){
    const float* x  = (const float*)d_in[0];
    const float* Wf = (const float*)d_in[1];
    const float* bf = (const float*)d_in[2];
    const float* Wi = (const float*)d_in[3];
    const float* bi = (const float*)d_in[4];
    const float* Wc = (const float*)d_in[5];
    const float* bc = (const float*)d_in[6];
    const float* Wo = (const float*)d_in[7];
    const float* bo = (const float*)d_in[8];

    // ws: Wfrag 442368 | xbf 16777216 | cbuf 8388608 | hbfA 4194304 | hbfB 4194304
    unsigned short* Wfrag = (unsigned short*)d_ws;
    unsigned short* xbf   = (unsigned short*)((char*)d_ws + 442368);
    float*          cbuf  = (float*)((char*)d_ws + 442368 + 16777216);
    unsigned short* hbfA  = (unsigned short*)((char*)d_ws + 442368 + 16777216 + 8388608);
    unsigned short* hbfB  = hbfA + CSTRIDE_;

    prep_wfrag<<<dim3(864), dim3(256), 0, stream>>>(Wf, Wi, Wc, Wo, bf, bi, bc, bo, Wfrag);
    prep_xbf<<<dim3(2048), dim3(256), 0, stream>>>(x, xbf);

    for (int t = 0; t < T_; ++t){
        const unsigned short* hi = (t & 1) ? hbfA : hbfB;   // t==0 never reads
        unsigned short*       ho = (t & 1) ? hbfB : hbfA;
        lstm_step<<<dim3(512), dim3(256), 0, stream>>>(
            xbf, Wfrag, cbuf, hi, ho, (float*)d_out, t);
    }
}